// Round 10
// baseline (386.205 us; speedup 1.0000x reference)
//
#include <hip/hip_runtime.h>
#include <hip/hip_bf16.h>

#define S 2048
#define DM 2048
#define NH 16
#define DH 128

typedef __attribute__((ext_vector_type(8))) short short8;
typedef __attribute__((ext_vector_type(4))) float floatx4;
typedef unsigned short u16;
typedef unsigned int u32;

__device__ __forceinline__ u16 f2bf(float f) {
  union { float f; u32 u; } v; v.f = f;
  u32 r = v.u + 0x7fffu + ((v.u >> 16) & 1u);
  return (u16)(r >> 16);
}
// HW packed round-to-nearest-even f32x2 -> bf16x2 (v_cvt_pk_bf16_f32)
__device__ __forceinline__ u32 pack2(float lo, float hi) {
  float2 f; f.x = lo; f.y = hi;
  __hip_bfloat162 h = __float22bfloat162_rn(f);
  union { __hip_bfloat162 h; u32 u; } c; c.h = h;
  return c.u;
}

__device__ __forceinline__ floatx4 mfma16(short8 a, short8 b, floatx4 c) {
  return __builtin_amdgcn_mfma_f32_16x16x32_bf16(a, b, c, 0, 0, 0);
}

// async global -> LDS, 16B per lane. LDS dest = wave-uniform base + lane*16.
__device__ __forceinline__ void async_cp16(const u16* g, u16* l) {
  __builtin_amdgcn_global_load_lds(
      (const __attribute__((address_space(1))) void*)g,
      (__attribute__((address_space(3))) void*)l, 16, 0, 0);
}

// ---------- convert x (fp32 -> bf16), 4 elems/thread ----------
__global__ void conv_x_k(const float* __restrict__ x, u16* __restrict__ xb) {
  int gid = blockIdx.x * 256 + threadIdx.x;
  float4 v = ((const float4*)x)[gid];
  uint2 p; p.x = pack2(v.x, v.y); p.y = pack2(v.z, v.w);
  ((uint2*)xb)[gid] = p;
}

// ---------- transpose+convert weights: Wt[n*2048+k] = bf16(W[k*2048+n]) ----------
__global__ void conv_w_k(const float* __restrict__ W0, const float* __restrict__ W1,
                         const float* __restrict__ W2, const float* __restrict__ W3,
                         u16* __restrict__ out) {
  __shared__ float tile[32][33];
  const float* W = blockIdx.z == 0 ? W0 : blockIdx.z == 1 ? W1 : blockIdx.z == 2 ? W2 : W3;
  u16* O = out + (size_t)blockIdx.z * DM * DM;
  int tx = threadIdx.x & 31, ty = threadIdx.x >> 5;
  int k0 = blockIdx.y * 32, n0 = blockIdx.x * 32;
#pragma unroll
  for (int j = 0; j < 4; j++)
    tile[ty + j * 8][tx] = W[(size_t)(k0 + ty + j * 8) * DM + n0 + tx];
  __syncthreads();
#pragma unroll
  for (int j = 0; j < 4; j++)
    O[(size_t)(n0 + ty + j * 8) * DM + k0 + tx] = f2bf(tile[tx][ty + j * 8]);
}

// ---------- 256x128 bf16 MFMA GEMM, BK=32, 2 blocks/CU (QKV) ----------
// Best measured config (r8: 131.5 us, MfmaUtil 33%). GEMM lane exhausted
// after 5 structural variants all landing 28-33%; kept as-is.
#define BM 256
#define BN 128
#define BK 32
#define NT 64

#define BARRIER __builtin_amdgcn_s_barrier()
#define SB __builtin_amdgcn_sched_barrier(0)
#define LGKM0 asm volatile("s_waitcnt lgkmcnt(0)" ::: "memory")

#define STG_A(q, j, koff) \
  async_cp16(pAg + (size_t)(j) * 64 * DM + (koff), &As[q][soff + (j) * 2048])
#define STG_B(q, j, koff) \
  async_cp16(pBg + (size_t)(j) * 64 * DM + (koff), &Bs[q][soff + (j) * 2048])

#define PH0(p) { \
    a0 = *(const short8*)&As[p][arow + xk]; \
    a1 = *(const short8*)&As[p][arow + 512 + xk]; \
    a2 = *(const short8*)&As[p][arow + 1024 + xk]; \
    a3 = *(const short8*)&As[p][arow + 1536 + xk]; \
    a4 = *(const short8*)&As[p][arow + 2048 + xk]; \
    a5 = *(const short8*)&As[p][arow + 2560 + xk]; \
    a6 = *(const short8*)&As[p][arow + 3072 + xk]; \
    a7 = *(const short8*)&As[p][arow + 3584 + xk]; \
    b0 = *(const short8*)&Bs[p][brow + xk]; \
    b1 = *(const short8*)&Bs[p][brow + 512 + xk]; \
    b2 = *(const short8*)&Bs[p][brow + 1024 + xk]; \
    b3 = *(const short8*)&Bs[p][brow + 1536 + xk]; \
    BARRIER; LGKM0; SB; \
    __builtin_amdgcn_s_setprio(1); \
    acc[0][0] = mfma16(a0, b0, acc[0][0]); \
    acc[1][0] = mfma16(a1, b0, acc[1][0]); \
    acc[2][0] = mfma16(a2, b0, acc[2][0]); \
    acc[3][0] = mfma16(a3, b0, acc[3][0]); \
    acc[0][1] = mfma16(a0, b1, acc[0][1]); \
    acc[1][1] = mfma16(a1, b1, acc[1][1]); \
    acc[2][1] = mfma16(a2, b1, acc[2][1]); \
    acc[3][1] = mfma16(a3, b1, acc[3][1]); \
    acc[0][2] = mfma16(a0, b2, acc[0][2]); \
    acc[1][2] = mfma16(a1, b2, acc[1][2]); \
    acc[2][2] = mfma16(a2, b2, acc[2][2]); \
    acc[3][2] = mfma16(a3, b2, acc[3][2]); \
    acc[0][3] = mfma16(a0, b3, acc[0][3]); \
    acc[1][3] = mfma16(a1, b3, acc[1][3]); \
    acc[2][3] = mfma16(a2, b3, acc[2][3]); \
    acc[3][3] = mfma16(a3, b3, acc[3][3]); \
    __builtin_amdgcn_s_setprio(0); \
    BARRIER; }

#define PH1(p, koff2, PRE2, LAST) { \
    if (PRE2) { STG_B(p, 0, koff2); STG_B(p, 1, koff2); \
                STG_A(p, 0, koff2); STG_A(p, 1, koff2); \
                STG_A(p, 2, koff2); STG_A(p, 3, koff2); } \
    SB; \
    __builtin_amdgcn_s_setprio(1); \
    acc[4][0] = mfma16(a4, b0, acc[4][0]); \
    acc[5][0] = mfma16(a5, b0, acc[5][0]); \
    acc[6][0] = mfma16(a6, b0, acc[6][0]); \
    acc[7][0] = mfma16(a7, b0, acc[7][0]); \
    acc[4][1] = mfma16(a4, b1, acc[4][1]); \
    acc[5][1] = mfma16(a5, b1, acc[5][1]); \
    acc[6][1] = mfma16(a6, b1, acc[6][1]); \
    acc[7][1] = mfma16(a7, b1, acc[7][1]); \
    acc[4][2] = mfma16(a4, b2, acc[4][2]); \
    acc[5][2] = mfma16(a5, b2, acc[5][2]); \
    acc[6][2] = mfma16(a6, b2, acc[6][2]); \
    acc[7][2] = mfma16(a7, b2, acc[7][2]); \
    acc[4][3] = mfma16(a4, b3, acc[4][3]); \
    acc[5][3] = mfma16(a5, b3, acc[5][3]); \
    acc[6][3] = mfma16(a6, b3, acc[6][3]); \
    acc[7][3] = mfma16(a7, b3, acc[7][3]); \
    __builtin_amdgcn_s_setprio(0); SB; \
    if (!LAST) { \
      if (PRE2) { asm volatile("s_waitcnt vmcnt(6)" ::: "memory"); } \
      else      { asm volatile("s_waitcnt vmcnt(0)" ::: "memory"); } \
      BARRIER; SB; } }

__global__ __launch_bounds__(256, 2)
void gemm_k(const u16* __restrict__ A, const u16* __restrict__ Wt,
            u16* __restrict__ oQ, u16* __restrict__ oK, u16* __restrict__ oV,
            const int* __restrict__ tp)
{
  __shared__ u16 As[2][BM * BK];   // 2 x 16 KiB
  __shared__ u16 Bs[2][BN * BK];   // 2 x 8 KiB -> 48 KiB total
  const int t = threadIdx.x;
  const int w = t >> 6, lane = t & 63;
  const int l16 = lane & 15, quad = lane >> 4;
  const int wr = w >> 1, wc = w & 1;     // 2M x 2N waves, 128x64 each
  const int m0 = blockIdx.y * BM, n0 = blockIdx.x * BN;
  const u16* Bt = Wt + (size_t)blockIdx.z * DM * DM;

  const int srow = t >> 2;
  const int sc = ((t & 3) ^ ((t >> 3) & 3)) * 8;
  const u16* pAg = A + (size_t)(m0 + srow) * DM + sc;
  const u16* pBg = Bt + (size_t)(n0 + srow) * DM + sc;
  const int soff = t * 8;

  const int arow = (wr * 128 + l16) * 32;
  const int brow = (wc * 64 + l16) * 32;
  const int xk = ((quad ^ ((l16 >> 1) & 3)) << 3);

  floatx4 acc[8][4] = {};
  short8 a0, a1, a2, a3, a4, a5, a6, a7, b0, b1, b2, b3;

  // ---- prologue: stage T0 -> buf0, T1 -> buf1 (6 loads each); wait T0 only
  STG_B(0, 0, 0); STG_B(0, 1, 0);
  STG_A(0, 0, 0); STG_A(0, 1, 0); STG_A(0, 2, 0); STG_A(0, 3, 0);
  STG_B(1, 0, BK); STG_B(1, 1, BK);
  STG_A(1, 0, BK); STG_A(1, 1, BK); STG_A(1, 2, BK); STG_A(1, 3, BK);
  SB;
  asm volatile("s_waitcnt vmcnt(6)" ::: "memory");
  BARRIER; SB;

  for (int it = 0; it < 31; ++it) {
    const int kE = (2 * it + 2) * BK;
    const int kO = (2 * it + 3) * BK;
    PH0(0) PH1(0, kE, 1, 0)
    PH0(1) PH1(1, kO, 1, 0)
  }
  PH0(0) PH1(0, 0, 0, 0)                 // tile 62: drain for tile 63
  PH0(1) PH1(1, 0, 0, 1)                 // tile 63: clean

  // ---- epilogue
  const int mwb = m0 + wr * 128;
  const int nwb = n0 + wc * 64;
  if ((int)blockIdx.z == 2) {
#pragma unroll
    for (int mi = 0; mi < 8; mi++) {
      int m = mwb + mi * 16 + quad * 4;
      int b = m >> 11, s = m & (S - 1);
#pragma unroll
      for (int ni = 0; ni < 4; ni++) {
        int f = nwb + ni * 16 + l16;
        int h = f >> 7, dh = f & (DH - 1);
        uint2 pk; pk.x = pack2(acc[mi][ni][0], acc[mi][ni][1]);
        pk.y = pack2(acc[mi][ni][2], acc[mi][ni][3]);
        *(uint2*)&oV[((size_t)(b * NH + h) * DH + dh) * S + s] = pk;
      }
    }
  } else {
    // RoPE fused; for Q (z==0) also fold 1/sqrt(dk)*log2(e) into the value
    u16* Out = ((int)blockIdx.z == 0) ? oQ : oK;
    const float qs = ((int)blockIdx.z == 0) ? 0.12752780f : 1.0f;
#pragma unroll
    for (int mi = 0; mi < 8; mi++) {
#pragma unroll
      for (int r = 0; r < 4; r++) {
        int m = mwb + mi * 16 + quad * 4 + r;
        int b = m >> 11, s = m & (S - 1);
        int ps = tp[s];
#pragma unroll
        for (int ni = 0; ni < 4; ni++) {
          int f = nwb + ni * 16 + l16;
          int h = f >> 7, dh = f & (DH - 1);
          float own = acc[mi][ni][r];
          float oth = __shfl_xor(own, 1, 64);
          float fr = __expf((float)(dh & ~1) * (-9.210340371976184f / 128.0f));
          float ang = (float)ps * fr;
          float sn, cs; __sincosf(ang, &sn, &cs);
          float res = (dh & 1) ? (oth * sn + own * cs) : (own * cs - oth * sn);
          Out[((size_t)(b * NH + h) * S + s) * DH + dh] = f2bf(res * qs);
        }
      }
    }
  }
}

// ---------- O-projection: 128x128 bf16 MFMA GEMM, 4 blocks/CU ----------
__global__ __launch_bounds__(256, 4)
void oproj_k(const u16* __restrict__ A, const u16* __restrict__ Wt,
             float* __restrict__ oO)
{
  __shared__ u16 As2[128 * 32];
  __shared__ u16 Bs2[128 * 32];
  const int t = threadIdx.x;
  const int w = t >> 6, lane = t & 63;
  const int l16 = lane & 15, quad = lane >> 4;
  const int m0 = blockIdx.y * 128, n0 = blockIdx.x * 128;
  const int wm = (w >> 1) * 64, wn = (w & 1) * 64;
  const u16* Bt = Wt + (size_t)3 * DM * DM;

  const u16* pA[2]; const u16* pB[2]; u16* lA[2]; u16* lB[2];
#pragma unroll
  for (int i = 0; i < 2; i++) {
    int unit = i * 256 + t;
    int row = unit >> 2, s = unit & 3;
    int c = s ^ ((row >> 1) & 3);
    pA[i] = A + (size_t)(m0 + row) * DM + c * 8;
    pB[i] = Bt + (size_t)(n0 + row) * DM + c * 8;
    lA[i] = &As2[unit * 8];
    lB[i] = &Bs2[unit * 8];
  }

  floatx4 acc[4][4] = {};

  for (int k0 = 0; k0 < DM; k0 += 32) {
#pragma unroll
    for (int i = 0; i < 2; i++) {
      async_cp16(pA[i] + k0, lA[i]);
      async_cp16(pB[i] + k0, lB[i]);
    }
    __syncthreads();
    short8 af[4], bfr[4];
#pragma unroll
    for (int i = 0; i < 4; i++) {
      int row = wm + i * 16 + l16;
      af[i] = *(short8*)&As2[(row * 4 + (quad ^ ((row >> 1) & 3))) * 8];
    }
#pragma unroll
    for (int i = 0; i < 4; i++) {
      int row = wn + i * 16 + l16;
      bfr[i] = *(short8*)&Bs2[(row * 4 + (quad ^ ((row >> 1) & 3))) * 8];
    }
#pragma unroll
    for (int mi = 0; mi < 4; mi++)
#pragma unroll
      for (int ni = 0; ni < 4; ni++)
        acc[mi][ni] = mfma16(af[mi], bfr[ni], acc[mi][ni]);
    __syncthreads();
  }

#pragma unroll
  for (int mi = 0; mi < 4; mi++) {
    int m = m0 + wm + mi * 16 + quad * 4;
#pragma unroll
    for (int ni = 0; ni < 4; ni++) {
      int n = n0 + wn + ni * 16 + l16;
#pragma unroll
      for (int r = 0; r < 4; r++)
        oO[(size_t)(m + r) * DM + n] = acc[mi][ni][r];
    }
  }
}

// ---------- causal flash attention v9: 32 q/wave (2 q-frags), QBLK=128 ----------
// v8 -> v9: each wave owns 32 q rows (2 fragments), so the 16 K-frag and 16
// V-frag ds_read_b128 per tile feed 64 MFMA instead of 32 (0.56 reads/MFMA),
// and each staged K/V tile serves 128 q rows (HBM/L2 fetch traffic halved).
// 512 blocks: task mapping pairs big (nt=32-2s) with small (nt=2s+2) so both
// resident blocks of a CU sum to 34 tile-units (uniform makespan at exactly
// 2 blocks/CU x 80 KiB LDS). Fully-masked tiles (k0a > qt+31) are skipped at
// wave level (k0a, qt wave-uniform) while barriers/staging stay uniform.
// Sync skeleton identical to v8: dbuf K/V, stage tile i+2 into own buffer
// after the reads drain, boundary vmcnt(8) -- never drains mid-loop.
#define ATILE(p, i) { \
    const int k0a = (i) * 64; \
    if (k0a <= qt + 31) { \
      _Pragma("unroll") \
      for (int hh = 0; hh < 4; hh++) { \
        int row = hh * 16 + l16; \
        floatx4 s0 = {0.f, 0.f, 0.f, 0.f}; \
        floatx4 s1 = {0.f, 0.f, 0.f, 0.f}; \
        __builtin_amdgcn_s_setprio(1); \
        _Pragma("unroll") \
        for (int kc = 0; kc < 4; kc++) { \
          short8 kf = *(short8*)&Ks[p][row * 128 + (((kc * 4 + quad) ^ l16) << 3)]; \
          s0 = mfma16(kf, aq0[kc], s0); \
          s1 = mfma16(kf, aq1[kc], s1); \
        } \
        __builtin_amdgcn_s_setprio(0); \
        if (k0a + 64 > qt) { \
          _Pragma("unroll") \
          for (int r = 0; r < 4; r++) { \
            int jj = k0a + hh * 16 + quad * 4 + r; \
            if (jj > qt + l16) s0[r] = -3.0e38f; \
            if (jj > qt + 16 + l16) s1[r] = -3.0e38f; \
          } \
        } \
        int su = (2 * hh + (quad >> 1)) ^ pxor; \
        float e0 = __builtin_amdgcn_exp2f(fminf(s0[0], 44.0f)); \
        float e1 = __builtin_amdgcn_exp2f(fminf(s0[1], 44.0f)); \
        float e2 = __builtin_amdgcn_exp2f(fminf(s0[2], 44.0f)); \
        float e3 = __builtin_amdgcn_exp2f(fminf(s0[3], 44.0f)); \
        lsum0 += (e0 + e1) + (e2 + e3); \
        uint2 pk0; pk0.x = pack2(e0, e1); pk0.y = pack2(e2, e3); \
        *(uint2*)&Pw[l16 * 64 + su * 8 + (quad & 1) * 4] = pk0; \
        e0 = __builtin_amdgcn_exp2f(fminf(s1[0], 44.0f)); \
        e1 = __builtin_amdgcn_exp2f(fminf(s1[1], 44.0f)); \
        e2 = __builtin_amdgcn_exp2f(fminf(s1[2], 44.0f)); \
        e3 = __builtin_amdgcn_exp2f(fminf(s1[3], 44.0f)); \
        lsum1 += (e0 + e1) + (e2 + e3); \
        uint2 pk1; pk1.x = pack2(e0, e1); pk1.y = pack2(e2, e3); \
        *(uint2*)&Pw[(16 + l16) * 64 + su * 8 + (quad & 1) * 4] = pk1; \
      } \
    } \
    LGKM0; SB; \
    BARRIER;                       /* all waves done reading Ks[p] */ \
    if ((i) + 2 < nt) { \
      _Pragma("unroll") \
      for (int j = 0; j < 4; j++) \
        async_cp16(pK[j] + (size_t)(k0a + 128) * DH, &Ks[p][lKo[j]]); \
    } \
    if (k0a <= qt + 31) { \
      __builtin_amdgcn_s_setprio(1); \
      _Pragma("unroll") \
      for (int c = 0; c < 2; c++) { \
        short8 pf0 = *(short8*)&Pw[l16 * 64 + (((4 * c + quad) ^ pxor) << 3)]; \
        short8 pf1 = *(short8*)&Pw[(16 + l16) * 64 + (((4 * c + quad) ^ pxor) << 3)]; \
        _Pragma("unroll") \
        for (int t8 = 0; t8 < 8; t8++) { \
          int row = t8 * 16 + l16; \
          short8 av = *(short8*)&Vs[p][row * 64 + (((c * 4 + quad) ^ (l16 & 7)) << 3)]; \
          o0[t8] = mfma16(av, pf0, o0[t8]); \
          o1[t8] = mfma16(av, pf1, o1[t8]); \
        } \
      } \
      __builtin_amdgcn_s_setprio(0); \
    } \
    LGKM0; SB; \
    BARRIER;                       /* all waves done reading Vs[p] */ \
    if ((i) + 2 < nt) { \
      _Pragma("unroll") \
      for (int j = 0; j < 4; j++) \
        async_cp16(pV[j] + k0a + 128, &Vs[p][lVo[j]]); \
    } \
    if ((i) + 1 < nt) { \
      SB; \
      if ((i) + 2 < nt) { asm volatile("s_waitcnt vmcnt(8)" ::: "memory"); } \
      else              { asm volatile("s_waitcnt vmcnt(0)" ::: "memory"); } \
      BARRIER; SB; \
    } \
  }

__global__ __launch_bounds__(256, 2)
void attn_k(const u16* __restrict__ Q, const u16* __restrict__ K,
            const u16* __restrict__ Vt, u16* __restrict__ O)
{
  __shared__ u16 Ks[2][64 * 128];  // key-major, swizzle: unit r*16 + (c ^ (r&15))
  __shared__ u16 Vs[2][128 * 64];  // dh-major,  swizzle: unit r*8  + (c ^ (r&7))
  __shared__ u16 P[4][32 * 64];    // per-wave 32 q x 64 keys, 16B-XOR-swizzled
  const int t = threadIdx.x, w = t >> 6, lane = t & 63;
  const int l16 = lane & 15, quad = lane >> 4;
  const int task = blockIdx.x;
  // pairing map: tasks 0..255 big (nt 32..18, dispatched first), 256..511
  // small (nt 2..16); task i and i+256 sum to 34 tile-units per CU.
  const int half = task >> 8, idx = task & 255;
  const int slot = idx >> 5, bh = idx & 31;
  const int b = bh >> 4, h = bh & 15;
  const int gq = half ? slot : (15 - slot);
  const int qg = gq * 128;
  const int qt = qg + w * 32;
  const int nt = 2 * gq + 2;             // k-tiles (always even, >= 2)
  const u16* Qb = Q + (size_t)bh * S * DH;
  const u16* Kb = K + (size_t)bh * S * DH;
  const u16* Vb = Vt + (size_t)bh * DH * S;
  u16* Pw = P[w];
  const int pxor = l16 & 7;

  const u16* pK[4]; int lKo[4];
  const u16* pV[4]; int lVo[4];
#pragma unroll
  for (int j = 0; j < 4; j++) {
    int kr = w * 16 + j * 4 + quad;
    int ks = l16;
    int kc = ks ^ (kr & 15);
    pK[j] = Kb + (size_t)kr * DH + kc * 8;
    lKo[j] = kr * 128 + ks * 8;
    int vr = w * 32 + j * 8 + (lane >> 3);
    int vs = lane & 7;
    int vc = vs ^ (vr & 7);
    pV[j] = Vb + (size_t)vr * S + vc * 8;
    lVo[j] = vr * 64 + vs * 8;
  }

  short8 aq0[4], aq1[4];
#pragma unroll
  for (int kc = 0; kc < 4; kc++) {
    aq0[kc] = *(const short8*)&Qb[(size_t)(qt + l16) * DH + kc * 32 + quad * 8];
    aq1[kc] = *(const short8*)&Qb[(size_t)(qt + 16 + l16) * DH + kc * 32 + quad * 8];
  }

  floatx4 o0[8] = {}, o1[8] = {};
  float lsum0 = 0.0f, lsum1 = 0.0f;

  // ---- prologue: stage T0 -> buf0, T1 -> buf1 (nt >= 2 always); wait T0 only
#pragma unroll
  for (int j = 0; j < 4; j++) async_cp16(pK[j], &Ks[0][lKo[j]]);
#pragma unroll
  for (int j = 0; j < 4; j++) async_cp16(pV[j], &Vs[0][lVo[j]]);
#pragma unroll
  for (int j = 0; j < 4; j++) async_cp16(pK[j] + (size_t)64 * DH, &Ks[1][lKo[j]]);
#pragma unroll
  for (int j = 0; j < 4; j++) async_cp16(pV[j] + 64, &Vs[1][lVo[j]]);
  SB;
  asm volatile("s_waitcnt vmcnt(8)" ::: "memory");
  BARRIER; SB;

  for (int i = 0; i < nt; i += 2) {
    ATILE(0, i)
    ATILE(1, i + 1)
  }

  // ---- epilogue: reduce l across quads ONCE per frag, then scale and store
  float l0 = lsum0 + __shfl_xor(lsum0, 16, 64);
  l0 += __shfl_xor(l0, 32, 64);
  float l1 = lsum1 + __shfl_xor(lsum1, 16, 64);
  l1 += __shfl_xor(l1, 32, 64);
  float inv0 = __builtin_amdgcn_rcpf(l0);
  float inv1 = __builtin_amdgcn_rcpf(l1);
#pragma unroll
  for (int t8 = 0; t8 < 8; t8++) {
    uint2 pa;
    pa.x = pack2(o0[t8][0] * inv0, o0[t8][1] * inv0);
    pa.y = pack2(o0[t8][2] * inv0, o0[t8][3] * inv0);
    *(uint2*)&O[((size_t)(b * S + qt + l16)) * DM + h * DH + t8 * 16 + quad * 4] = pa;
    pa.x = pack2(o1[t8][0] * inv1, o1[t8][1] * inv1);
    pa.y = pack2(o1[t8][2] * inv1, o1[t8][3] * inv1);
    *(uint2*)&O[((size_t)(b * S + qt + 16 + l16)) * DM + h * DH + t8 * 16 + quad * 4] = pa;
  }
}

extern "C" void kernel_launch(void* const* d_in, const int* in_sizes, int n_in,
                              void* d_out, int out_size, void* d_ws, size_t ws_size,
                              hipStream_t stream) {
  const float* x  = (const float*)d_in[0];
  const float* Wq = (const float*)d_in[1];
  const float* Wk = (const float*)d_in[2];
  const float* Wv = (const float*)d_in[3];
  const float* Wo = (const float*)d_in[4];
  const int*   tp = (const int*)d_in[5];

  char* ws = (char*)d_ws;
  u16* Wt = (u16*)ws;
  u16* xb = (u16*)(ws + 33554432);
  u16* Qb = (u16*)(ws + 50331648);
  u16* Kb = (u16*)(ws + 67108864);
  u16* Vb = (u16*)(ws + 83886080);
  u16* Ob = (u16*)(ws + 100663296);

  conv_x_k<<<8192, 256, 0, stream>>>(x, xb);
  conv_w_k<<<dim3(64, 64, 4), 256, 0, stream>>>(Wq, Wk, Wv, Wo, Wt);
  gemm_k<<<dim3(16, 16, 3), 256, 0, stream>>>(xb, Wt, Qb, Kb, Vb, tp);
  attn_k<<<512, 256, 0, stream>>>(Qb, Kb, Vb, Ob);
  oproj_k<<<dim3(16, 32), 256, 0, stream>>>(Ob, Wt, (float*)d_out);
}

// Round 11
// 363.161 us; speedup vs baseline: 1.0635x; 1.0635x over previous
//
#include <hip/hip_runtime.h>
#include <hip/hip_bf16.h>

#define S 2048
#define DM 2048
#define NH 16
#define DH 128

typedef __attribute__((ext_vector_type(8))) short short8;
typedef __attribute__((ext_vector_type(4))) float floatx4;
typedef unsigned short u16;
typedef unsigned int u32;

__device__ __forceinline__ u16 f2bf(float f) {
  union { float f; u32 u; } v; v.f = f;
  u32 r = v.u + 0x7fffu + ((v.u >> 16) & 1u);
  return (u16)(r >> 16);
}
// HW packed round-to-nearest-even f32x2 -> bf16x2 (v_cvt_pk_bf16_f32)
__device__ __forceinline__ u32 pack2(float lo, float hi) {
  float2 f; f.x = lo; f.y = hi;
  __hip_bfloat162 h = __float22bfloat162_rn(f);
  union { __hip_bfloat162 h; u32 u; } c; c.h = h;
  return c.u;
}

__device__ __forceinline__ floatx4 mfma16(short8 a, short8 b, floatx4 c) {
  return __builtin_amdgcn_mfma_f32_16x16x32_bf16(a, b, c, 0, 0, 0);
}

// async global -> LDS, 16B per lane. LDS dest = wave-uniform base + lane*16.
__device__ __forceinline__ void async_cp16(const u16* g, u16* l) {
  __builtin_amdgcn_global_load_lds(
      (const __attribute__((address_space(1))) void*)g,
      (__attribute__((address_space(3))) void*)l, 16, 0, 0);
}

// ---------- convert x (fp32 -> bf16), 4 elems/thread ----------
__global__ void conv_x_k(const float* __restrict__ x, u16* __restrict__ xb) {
  int gid = blockIdx.x * 256 + threadIdx.x;
  float4 v = ((const float4*)x)[gid];
  uint2 p; p.x = pack2(v.x, v.y); p.y = pack2(v.z, v.w);
  ((uint2*)xb)[gid] = p;
}

// ---------- transpose+convert weights: Wt[n*2048+k] = bf16(W[k*2048+n]) ----------
__global__ void conv_w_k(const float* __restrict__ W0, const float* __restrict__ W1,
                         const float* __restrict__ W2, const float* __restrict__ W3,
                         u16* __restrict__ out) {
  __shared__ float tile[32][33];
  const float* W = blockIdx.z == 0 ? W0 : blockIdx.z == 1 ? W1 : blockIdx.z == 2 ? W2 : W3;
  u16* O = out + (size_t)blockIdx.z * DM * DM;
  int tx = threadIdx.x & 31, ty = threadIdx.x >> 5;
  int k0 = blockIdx.y * 32, n0 = blockIdx.x * 32;
#pragma unroll
  for (int j = 0; j < 4; j++)
    tile[ty + j * 8][tx] = W[(size_t)(k0 + ty + j * 8) * DM + n0 + tx];
  __syncthreads();
#pragma unroll
  for (int j = 0; j < 4; j++)
    O[(size_t)(n0 + ty + j * 8) * DM + k0 + tx] = f2bf(tile[tx][ty + j * 8]);
}

// ---------- 256x128 bf16 MFMA GEMM, BK=32, 2 blocks/CU (QKV) ----------
// r8 config (131.5 us, MfmaUtil 33%) + r11 tweak: the pre-MFMA lgkmcnt(0)
// drain moved to AFTER the MFMA cluster (before the closing barrier).
// Rationale: the 12 ds_reads are plain C++ loads, so the compiler emits
// incremental lgkmcnt(N) before each dependent MFMA (m97 behavior) -- the
// first MFMAs start while later reads are in flight. The trailing LGKM0
// preserves the WAR guard (wave's buf-p reads drained before any wave
// passes the barrier into PH1's staging of buf p) at ~zero cost.
#define BM 256
#define BN 128
#define BK 32
#define NT 64

#define BARRIER __builtin_amdgcn_s_barrier()
#define SB __builtin_amdgcn_sched_barrier(0)
#define LGKM0 asm volatile("s_waitcnt lgkmcnt(0)" ::: "memory")

#define STG_A(q, j, koff) \
  async_cp16(pAg + (size_t)(j) * 64 * DM + (koff), &As[q][soff + (j) * 2048])
#define STG_B(q, j, koff) \
  async_cp16(pBg + (size_t)(j) * 64 * DM + (koff), &Bs[q][soff + (j) * 2048])

#define PH0(p) { \
    a0 = *(const short8*)&As[p][arow + xk]; \
    a1 = *(const short8*)&As[p][arow + 512 + xk]; \
    a2 = *(const short8*)&As[p][arow + 1024 + xk]; \
    a3 = *(const short8*)&As[p][arow + 1536 + xk]; \
    a4 = *(const short8*)&As[p][arow + 2048 + xk]; \
    a5 = *(const short8*)&As[p][arow + 2560 + xk]; \
    a6 = *(const short8*)&As[p][arow + 3072 + xk]; \
    a7 = *(const short8*)&As[p][arow + 3584 + xk]; \
    b0 = *(const short8*)&Bs[p][brow + xk]; \
    b1 = *(const short8*)&Bs[p][brow + 512 + xk]; \
    b2 = *(const short8*)&Bs[p][brow + 1024 + xk]; \
    b3 = *(const short8*)&Bs[p][brow + 1536 + xk]; \
    BARRIER; \
    __builtin_amdgcn_s_setprio(1); \
    acc[0][0] = mfma16(a0, b0, acc[0][0]); \
    acc[1][0] = mfma16(a1, b0, acc[1][0]); \
    acc[2][0] = mfma16(a2, b0, acc[2][0]); \
    acc[3][0] = mfma16(a3, b0, acc[3][0]); \
    acc[0][1] = mfma16(a0, b1, acc[0][1]); \
    acc[1][1] = mfma16(a1, b1, acc[1][1]); \
    acc[2][1] = mfma16(a2, b1, acc[2][1]); \
    acc[3][1] = mfma16(a3, b1, acc[3][1]); \
    acc[0][2] = mfma16(a0, b2, acc[0][2]); \
    acc[1][2] = mfma16(a1, b2, acc[1][2]); \
    acc[2][2] = mfma16(a2, b2, acc[2][2]); \
    acc[3][2] = mfma16(a3, b2, acc[3][2]); \
    acc[0][3] = mfma16(a0, b3, acc[0][3]); \
    acc[1][3] = mfma16(a1, b3, acc[1][3]); \
    acc[2][3] = mfma16(a2, b3, acc[2][3]); \
    acc[3][3] = mfma16(a3, b3, acc[3][3]); \
    __builtin_amdgcn_s_setprio(0); \
    LGKM0; SB; \
    BARRIER; }

#define PH1(p, koff2, PRE2, LAST) { \
    if (PRE2) { STG_B(p, 0, koff2); STG_B(p, 1, koff2); \
                STG_A(p, 0, koff2); STG_A(p, 1, koff2); \
                STG_A(p, 2, koff2); STG_A(p, 3, koff2); } \
    SB; \
    __builtin_amdgcn_s_setprio(1); \
    acc[4][0] = mfma16(a4, b0, acc[4][0]); \
    acc[5][0] = mfma16(a5, b0, acc[5][0]); \
    acc[6][0] = mfma16(a6, b0, acc[6][0]); \
    acc[7][0] = mfma16(a7, b0, acc[7][0]); \
    acc[4][1] = mfma16(a4, b1, acc[4][1]); \
    acc[5][1] = mfma16(a5, b1, acc[5][1]); \
    acc[6][1] = mfma16(a6, b1, acc[6][1]); \
    acc[7][1] = mfma16(a7, b1, acc[7][1]); \
    acc[4][2] = mfma16(a4, b2, acc[4][2]); \
    acc[5][2] = mfma16(a5, b2, acc[5][2]); \
    acc[6][2] = mfma16(a6, b2, acc[6][2]); \
    acc[7][2] = mfma16(a7, b2, acc[7][2]); \
    acc[4][3] = mfma16(a4, b3, acc[4][3]); \
    acc[5][3] = mfma16(a5, b3, acc[5][3]); \
    acc[6][3] = mfma16(a6, b3, acc[6][3]); \
    acc[7][3] = mfma16(a7, b3, acc[7][3]); \
    __builtin_amdgcn_s_setprio(0); SB; \
    if (!LAST) { \
      if (PRE2) { asm volatile("s_waitcnt vmcnt(6)" ::: "memory"); } \
      else      { asm volatile("s_waitcnt vmcnt(0)" ::: "memory"); } \
      BARRIER; SB; } }

__global__ __launch_bounds__(256, 2)
void gemm_k(const u16* __restrict__ A, const u16* __restrict__ Wt,
            u16* __restrict__ oQ, u16* __restrict__ oK, u16* __restrict__ oV,
            const int* __restrict__ tp)
{
  __shared__ u16 As[2][BM * BK];   // 2 x 16 KiB
  __shared__ u16 Bs[2][BN * BK];   // 2 x 8 KiB -> 48 KiB total
  const int t = threadIdx.x;
  const int w = t >> 6, lane = t & 63;
  const int l16 = lane & 15, quad = lane >> 4;
  const int wr = w >> 1, wc = w & 1;     // 2M x 2N waves, 128x64 each
  const int m0 = blockIdx.y * BM, n0 = blockIdx.x * BN;
  const u16* Bt = Wt + (size_t)blockIdx.z * DM * DM;

  const int srow = t >> 2;
  const int sc = ((t & 3) ^ ((t >> 3) & 3)) * 8;
  const u16* pAg = A + (size_t)(m0 + srow) * DM + sc;
  const u16* pBg = Bt + (size_t)(n0 + srow) * DM + sc;
  const int soff = t * 8;

  const int arow = (wr * 128 + l16) * 32;
  const int brow = (wc * 64 + l16) * 32;
  const int xk = ((quad ^ ((l16 >> 1) & 3)) << 3);

  floatx4 acc[8][4] = {};
  short8 a0, a1, a2, a3, a4, a5, a6, a7, b0, b1, b2, b3;

  // ---- prologue: stage T0 -> buf0, T1 -> buf1 (6 loads each); wait T0 only
  STG_B(0, 0, 0); STG_B(0, 1, 0);
  STG_A(0, 0, 0); STG_A(0, 1, 0); STG_A(0, 2, 0); STG_A(0, 3, 0);
  STG_B(1, 0, BK); STG_B(1, 1, BK);
  STG_A(1, 0, BK); STG_A(1, 1, BK); STG_A(1, 2, BK); STG_A(1, 3, BK);
  SB;
  asm volatile("s_waitcnt vmcnt(6)" ::: "memory");
  BARRIER; SB;

  for (int it = 0; it < 31; ++it) {
    const int kE = (2 * it + 2) * BK;
    const int kO = (2 * it + 3) * BK;
    PH0(0) PH1(0, kE, 1, 0)
    PH0(1) PH1(1, kO, 1, 0)
  }
  PH0(0) PH1(0, 0, 0, 0)                 // tile 62: drain for tile 63
  PH0(1) PH1(1, 0, 0, 1)                 // tile 63: clean

  // ---- epilogue
  const int mwb = m0 + wr * 128;
  const int nwb = n0 + wc * 64;
  if ((int)blockIdx.z == 2) {
#pragma unroll
    for (int mi = 0; mi < 8; mi++) {
      int m = mwb + mi * 16 + quad * 4;
      int b = m >> 11, s = m & (S - 1);
#pragma unroll
      for (int ni = 0; ni < 4; ni++) {
        int f = nwb + ni * 16 + l16;
        int h = f >> 7, dh = f & (DH - 1);
        uint2 pk; pk.x = pack2(acc[mi][ni][0], acc[mi][ni][1]);
        pk.y = pack2(acc[mi][ni][2], acc[mi][ni][3]);
        *(uint2*)&oV[((size_t)(b * NH + h) * DH + dh) * S + s] = pk;
      }
    }
  } else {
    // RoPE fused; for Q (z==0) also fold 1/sqrt(dk)*log2(e) into the value
    u16* Out = ((int)blockIdx.z == 0) ? oQ : oK;
    const float qs = ((int)blockIdx.z == 0) ? 0.12752780f : 1.0f;
#pragma unroll
    for (int mi = 0; mi < 8; mi++) {
#pragma unroll
      for (int r = 0; r < 4; r++) {
        int m = mwb + mi * 16 + quad * 4 + r;
        int b = m >> 11, s = m & (S - 1);
        int ps = tp[s];
#pragma unroll
        for (int ni = 0; ni < 4; ni++) {
          int f = nwb + ni * 16 + l16;
          int h = f >> 7, dh = f & (DH - 1);
          float own = acc[mi][ni][r];
          float oth = __shfl_xor(own, 1, 64);
          float fr = __expf((float)(dh & ~1) * (-9.210340371976184f / 128.0f));
          float ang = (float)ps * fr;
          float sn, cs; __sincosf(ang, &sn, &cs);
          float res = (dh & 1) ? (oth * sn + own * cs) : (own * cs - oth * sn);
          Out[((size_t)(b * NH + h) * S + s) * DH + dh] = f2bf(res * qs);
        }
      }
    }
  }
}

// ---------- O-projection: 128x128 bf16 MFMA GEMM, 4 blocks/CU ----------
__global__ __launch_bounds__(256, 4)
void oproj_k(const u16* __restrict__ A, const u16* __restrict__ Wt,
             float* __restrict__ oO)
{
  __shared__ u16 As2[128 * 32];
  __shared__ u16 Bs2[128 * 32];
  const int t = threadIdx.x;
  const int w = t >> 6, lane = t & 63;
  const int l16 = lane & 15, quad = lane >> 4;
  const int m0 = blockIdx.y * 128, n0 = blockIdx.x * 128;
  const int wm = (w >> 1) * 64, wn = (w & 1) * 64;
  const u16* Bt = Wt + (size_t)3 * DM * DM;

  const u16* pA[2]; const u16* pB[2]; u16* lA[2]; u16* lB[2];
#pragma unroll
  for (int i = 0; i < 2; i++) {
    int unit = i * 256 + t;
    int row = unit >> 2, s = unit & 3;
    int c = s ^ ((row >> 1) & 3);
    pA[i] = A + (size_t)(m0 + row) * DM + c * 8;
    pB[i] = Bt + (size_t)(n0 + row) * DM + c * 8;
    lA[i] = &As2[unit * 8];
    lB[i] = &Bs2[unit * 8];
  }

  floatx4 acc[4][4] = {};

  for (int k0 = 0; k0 < DM; k0 += 32) {
#pragma unroll
    for (int i = 0; i < 2; i++) {
      async_cp16(pA[i] + k0, lA[i]);
      async_cp16(pB[i] + k0, lB[i]);
    }
    __syncthreads();
    short8 af[4], bfr[4];
#pragma unroll
    for (int i = 0; i < 4; i++) {
      int row = wm + i * 16 + l16;
      af[i] = *(short8*)&As2[(row * 4 + (quad ^ ((row >> 1) & 3))) * 8];
    }
#pragma unroll
    for (int i = 0; i < 4; i++) {
      int row = wn + i * 16 + l16;
      bfr[i] = *(short8*)&Bs2[(row * 4 + (quad ^ ((row >> 1) & 3))) * 8];
    }
#pragma unroll
    for (int mi = 0; mi < 4; mi++)
#pragma unroll
      for (int ni = 0; ni < 4; ni++)
        acc[mi][ni] = mfma16(af[mi], bfr[ni], acc[mi][ni]);
    __syncthreads();
  }

#pragma unroll
  for (int mi = 0; mi < 4; mi++) {
    int m = m0 + wm + mi * 16 + quad * 4;
#pragma unroll
    for (int ni = 0; ni < 4; ni++) {
      int n = n0 + wn + ni * 16 + l16;
#pragma unroll
      for (int r = 0; r < 4; r++)
        oO[(size_t)(m + r) * DM + n] = acc[mi][ni][r];
    }
  }
}

// ---------- causal flash attention v8 (reverted from v9): dbuf K/V + counted vmcnt ----------
// v9's 32q/wave + static big/small pairing regressed (−17 us): the pairing
// assumed CU j receives blocks j and j+256, but dispatch order is undefined
// and 512 blocks on 512 slots leaves no backfill. v8's 1024 blocks over 512
// slots + LPT ordering self-balances via hardware backfill. Reverted exactly.
#define ATILE(p, i) { \
    const int k0a = (i) * 64; \
    floatx4 sc[4] = {}; \
    __builtin_amdgcn_s_setprio(1); \
    _Pragma("unroll") \
    for (int hh = 0; hh < 4; hh++) { \
      int row = hh * 16 + l16; \
      _Pragma("unroll") \
      for (int kc = 0; kc < 4; kc++) { \
        short8 kf = *(short8*)&Ks[p][row * 128 + (((kc * 4 + quad) ^ l16) << 3)]; \
        sc[hh] = mfma16(kf, aq[kc], sc[hh]); \
      } \
    } \
    __builtin_amdgcn_s_setprio(0); \
    if (k0a + 64 > qt) { \
      _Pragma("unroll") \
      for (int hh = 0; hh < 4; hh++) \
        _Pragma("unroll") \
        for (int r = 0; r < 4; r++) { \
          int j = k0a + hh * 16 + quad * 4 + r; \
          if (j > qt + l16) sc[hh][r] = -3.0e38f; \
        } \
    } \
    _Pragma("unroll") \
    for (int hh = 0; hh < 4; hh++) { \
      float e0 = __builtin_amdgcn_exp2f(fminf(sc[hh][0], 44.0f)); \
      float e1 = __builtin_amdgcn_exp2f(fminf(sc[hh][1], 44.0f)); \
      float e2 = __builtin_amdgcn_exp2f(fminf(sc[hh][2], 44.0f)); \
      float e3 = __builtin_amdgcn_exp2f(fminf(sc[hh][3], 44.0f)); \
      lsum += (e0 + e1) + (e2 + e3); \
      uint2 pk; pk.x = pack2(e0, e1); pk.y = pack2(e2, e3); \
      int su = (2 * hh + (quad >> 1)) ^ pxor; \
      *(uint2*)&Pw[l16 * 64 + su * 8 + (quad & 1) * 4] = pk; \
    } \
    LGKM0; SB; \
    BARRIER;                       /* all waves done reading Ks[p] */ \
    if ((i) + 2 < nt) { \
      _Pragma("unroll") \
      for (int j = 0; j < 4; j++) \
        async_cp16(pK[j] + (size_t)(k0a + 128) * DH, &Ks[p][lKo[j]]); \
    } \
    __builtin_amdgcn_s_setprio(1); \
    _Pragma("unroll") \
    for (int c = 0; c < 2; c++) { \
      short8 pf = *(short8*)&Pw[l16 * 64 + (((4 * c + quad) ^ pxor) << 3)]; \
      _Pragma("unroll") \
      for (int t8 = 0; t8 < 8; t8++) { \
        int row = t8 * 16 + l16; \
        short8 av = *(short8*)&Vs[p][row * 64 + (((c * 4 + quad) ^ (l16 & 7)) << 3)]; \
        o[t8] = mfma16(av, pf, o[t8]); \
      } \
    } \
    __builtin_amdgcn_s_setprio(0); \
    LGKM0; SB; \
    BARRIER;                       /* all waves done reading Vs[p] */ \
    if ((i) + 2 < nt) { \
      _Pragma("unroll") \
      for (int j = 0; j < 4; j++) \
        async_cp16(pV[j] + k0a + 128, &Vs[p][lVo[j]]); \
    } \
    if ((i) + 1 < nt) { \
      SB; \
      if ((i) + 2 < nt) { asm volatile("s_waitcnt vmcnt(8)" ::: "memory"); } \
      else              { asm volatile("s_waitcnt vmcnt(0)" ::: "memory"); } \
      BARRIER; SB; \
    } \
  }

__global__ __launch_bounds__(256, 2)
void attn_k(const u16* __restrict__ Q, const u16* __restrict__ K,
            const u16* __restrict__ Vt, u16* __restrict__ O)
{
  __shared__ u16 Ks[2][64 * 128];  // key-major, swizzle: unit r*16 + (c ^ (r&15))
  __shared__ u16 Vs[2][128 * 64];  // dh-major,  swizzle: unit r*8  + (c ^ (r&7))
  __shared__ u16 P[4][16 * 64];    // per-wave 16 q x 64 keys, 16B-XOR-swizzled
  const int t = threadIdx.x, w = t >> 6, lane = t & 63;
  const int l16 = lane & 15, quad = lane >> 4;
  const int task = blockIdx.x;
  const int bh = task & 31, b = bh >> 4, h = bh & 15;
  const int g = 31 - (task >> 5);        // big groups dispatch first (LPT)
  const int qg = g * 64;
  const int qt = qg + w * 16;
  const int nt = g + 1;                  // k-tiles for this block
  const u16* Qb = Q + (size_t)bh * S * DH;
  const u16* Kb = K + (size_t)bh * S * DH;
  const u16* Vb = Vt + (size_t)bh * DH * S;
  u16* Pw = P[w];
  const int pxor = l16 & 7;

  const u16* pK[4]; int lKo[4];
  const u16* pV[4]; int lVo[4];
#pragma unroll
  for (int j = 0; j < 4; j++) {
    int kr = w * 16 + j * 4 + quad;
    int ks = l16;
    int kc = ks ^ (kr & 15);
    pK[j] = Kb + (size_t)kr * DH + kc * 8;
    lKo[j] = kr * 128 + ks * 8;
    int vr = w * 32 + j * 8 + (lane >> 3);
    int vs = lane & 7;
    int vc = vs ^ (vr & 7);
    pV[j] = Vb + (size_t)vr * S + vc * 8;
    lVo[j] = vr * 64 + vs * 8;
  }

  short8 aq[4];
#pragma unroll
  for (int kc = 0; kc < 4; kc++)
    aq[kc] = *(const short8*)&Qb[(size_t)(qt + l16) * DH + kc * 32 + quad * 8];

  floatx4 o[8] = {};
  float lsum = 0.0f;

  // ---- prologue: stage T0 -> buf0 (and T1 -> buf1 if present); wait T0 only
#pragma unroll
  for (int j = 0; j < 4; j++) async_cp16(pK[j], &Ks[0][lKo[j]]);
#pragma unroll
  for (int j = 0; j < 4; j++) async_cp16(pV[j], &Vs[0][lVo[j]]);
  if (nt > 1) {
#pragma unroll
    for (int j = 0; j < 4; j++) async_cp16(pK[j] + (size_t)64 * DH, &Ks[1][lKo[j]]);
#pragma unroll
    for (int j = 0; j < 4; j++) async_cp16(pV[j] + 64, &Vs[1][lVo[j]]);
    SB;
    asm volatile("s_waitcnt vmcnt(8)" ::: "memory");
  } else {
    SB;
    asm volatile("s_waitcnt vmcnt(0)" ::: "memory");
  }
  BARRIER; SB;

  int i = 0;
  for (; i + 2 <= nt; i += 2) {
    ATILE(0, i)
    ATILE(1, i + 1)
  }
  if (i < nt) { ATILE(0, i) }

  // ---- epilogue: reduce l across quads ONCE, then scale and store
  float l = lsum + __shfl_xor(lsum, 16, 64);
  l += __shfl_xor(l, 32, 64);
  float inv = __builtin_amdgcn_rcpf(l);
#pragma unroll
  for (int t8 = 0; t8 < 8; t8++) {
    uint2 pa;
    pa.x = pack2(o[t8][0] * inv, o[t8][1] * inv);
    pa.y = pack2(o[t8][2] * inv, o[t8][3] * inv);
    *(uint2*)&O[((size_t)(b * S + qt + l16)) * DM + h * DH + t8 * 16 + quad * 4] = pa;
  }
}

extern "C" void kernel_launch(void* const* d_in, const int* in_sizes, int n_in,
                              void* d_out, int out_size, void* d_ws, size_t ws_size,
                              hipStream_t stream) {
  const float* x  = (const float*)d_in[0];
  const float* Wq = (const float*)d_in[1];
  const float* Wk = (const float*)d_in[2];
  const float* Wv = (const float*)d_in[3];
  const float* Wo = (const float*)d_in[4];
  const int*   tp = (const int*)d_in[5];

  char* ws = (char*)d_ws;
  u16* Wt = (u16*)ws;
  u16* xb = (u16*)(ws + 33554432);
  u16* Qb = (u16*)(ws + 50331648);
  u16* Kb = (u16*)(ws + 67108864);
  u16* Vb = (u16*)(ws + 83886080);
  u16* Ob = (u16*)(ws + 100663296);

  conv_x_k<<<8192, 256, 0, stream>>>(x, xb);
  conv_w_k<<<dim3(64, 64, 4), 256, 0, stream>>>(Wq, Wk, Wv, Wo, Wt);
  gemm_k<<<dim3(16, 16, 3), 256, 0, stream>>>(xb, Wt, Qb, Kb, Vb, tp);
  attn_k<<<1024, 256, 0, stream>>>(Qb, Kb, Vb, Ob);
  oproj_k<<<dim3(16, 32), 256, 0, stream>>>(Ob, Wt, (float*)d_out);
}